// Round 10
// baseline (294.335 us; speedup 1.0000x reference)
//
#include <hip/hip_runtime.h>
#include <stdint.h>
#include <math.h>

#define BB 2
#define SS 2048
#define HH 2048
#define NH 16
#define KVH 4
#define HD 128
#define BSZ (BB*SS)      // 4096
#define QW (NH*HD)       // 2048
#define KVW (KVH*HD)     // 512

typedef __attribute__((ext_vector_type(8))) short s16x8;   // 8 bf16 = 4 VGPRs
typedef __attribute__((ext_vector_type(4))) float f32x4;   // MFMA C/D

typedef const unsigned int __attribute__((address_space(1)))* gas_ptr;
typedef unsigned int __attribute__((address_space(3)))* las_ptr;

__device__ __forceinline__ unsigned short f2b(float x) {
    unsigned u = __builtin_bit_cast(unsigned, x);
    unsigned r = u + 0x7fffu + ((u >> 16) & 1u);   // round-to-nearest-even
    return (unsigned short)(r >> 16);
}
__device__ __forceinline__ float b2f(unsigned short h) {
    unsigned u = ((unsigned)h) << 16;
    return __builtin_bit_cast(float, u);
}

// async global->LDS, 16B per lane; LDS dest = wave-uniform base + lane*16
__device__ __forceinline__ void gload_lds16(const void* g, void* l) {
    __builtin_amdgcn_global_load_lds((gas_ptr)g, (las_ptr)l, 16, 0, 0);
}

// ===========================================================================
// True 8-phase GEMM (m201-style), BK=64, double-buffered, counted vmcnt.
// (unchanged from R7 — verified 294->273 µs)
// ===========================================================================
template<int FN>
__device__ __forceinline__ void stage_half(
    const unsigned short* __restrict__ src, int rowbase, int k0,
    unsigned short* dst)
{
    const int tid = threadIdx.x;
#pragma unroll
    for (int q = 0; q < 2; ++q) {
        int row = (tid >> 3) + q * 64;
        int sl  = (tid & 7) ^ (row & 7);
        gload_lds16(src + (size_t)(rowbase + row) * HH + k0 + sl * 8,
                    dst + (q * 512 + tid) * 8);
    }
}

__device__ __forceinline__ s16x8 ldsr(const unsigned short* base,
                                      int r, int kh, int quad)
{
    return *(const s16x8*)(base + r * 64 + (((kh * 4 + quad) ^ (r & 7)) * 8));
}

#define SBAR() do { __builtin_amdgcn_sched_barrier(0); \
                    __builtin_amdgcn_s_barrier();       \
                    __builtin_amdgcn_sched_barrier(0); } while (0)

template<int FN>
__device__ __forceinline__ void gemm8p(
    const unsigned short* __restrict__ A,
    const unsigned short* __restrict__ Bt,
    int m0, int c0, unsigned short* lds, f32x4 acc[8][FN])
{
    constexpr int NT    = HH / 64;            // 32 K-tiles
    constexpr int BUFE  = (2 + FN / 2) * 8192;
    constexpr int ABOFF = (FN / 2) * 8192;    // A region start (elements)
    const int tid  = threadIdx.x;
    const int lane = tid & 63, wave = tid >> 6;
    const int quad = lane >> 4, l15 = lane & 15;
    const int wm = wave >> 2, wn = wave & 3;
    const int arow0 = wm * 128 + l15;         // + fr*16
    const int brow0 = wn * (FN * 16) + l15;   // + fc*16

#pragma unroll
    for (int i = 0; i < 8; ++i)
#pragma unroll
        for (int fc = 0; fc < FN; ++fc) acc[i][fc] = (f32x4){0.f, 0.f, 0.f, 0.f};

    unsigned short* buf0 = lds;
    unsigned short* buf1 = lds + BUFE;

    // ---- prologue: B(0)[,B-hi(0)], A-lo(0), A-hi(0), B(1)[,B-hi(1)] ----
    stage_half<FN>(Bt, c0, 0, buf0);
    if constexpr (FN == 4) stage_half<FN>(Bt, c0 + 128, 0, buf0 + 8192);
    stage_half<FN>(A, m0, 0, buf0 + ABOFF);
    stage_half<FN>(A, m0 + 128, 0, buf0 + ABOFF + 8192);
    stage_half<FN>(Bt, c0, 64, buf1);
    if constexpr (FN == 4) {
        stage_half<FN>(Bt, c0 + 128, 64, buf1 + 8192);
        asm volatile("s_waitcnt vmcnt(4)" ::: "memory");  // tile 0 landed
    } else {
        asm volatile("s_waitcnt vmcnt(2)" ::: "memory");
    }
    SBAR();

#pragma unroll 2
    for (int T = 0; T < NT; ++T) {
        unsigned short* buf = (T & 1) ? buf1 : buf0;
        unsigned short* nbuf = (T & 1) ? buf0 : buf1;   // T+1 -> nbuf, T+2 -> buf
        const unsigned short* Bb = buf;
        const unsigned short* Ab = buf + ABOFF;
        const int k1 = (T + 1) * 64, k2 = (T + 2) * 64;

        // ---------------- phase 0 ----------------
        s16x8 b[FN][2], a01[2][2];
#pragma unroll
        for (int fc = 0; fc < FN; ++fc)
#pragma unroll
            for (int kh = 0; kh < 2; ++kh)
                b[fc][kh] = ldsr(Bb, brow0 + fc * 16, kh, quad);
#pragma unroll
        for (int fr = 0; fr < 2; ++fr)
#pragma unroll
            for (int kh = 0; kh < 2; ++kh)
                a01[fr][kh] = ldsr(Ab, arow0 + fr * 16, kh, quad);
        if (T + 1 < NT) stage_half<FN>(A, m0, k1, nbuf + ABOFF);
        SBAR();
        __builtin_amdgcn_s_setprio(1);
#pragma unroll
        for (int fr = 0; fr < 2; ++fr)
#pragma unroll
            for (int fc = 0; fc < FN; ++fc)
#pragma unroll
                for (int kh = 0; kh < 2; ++kh)
                    acc[fr][fc] = __builtin_amdgcn_mfma_f32_16x16x32_bf16(
                        a01[fr][kh], b[fc][kh], acc[fr][fc], 0, 0, 0);
        __builtin_amdgcn_s_setprio(0);
        SBAR();

        // ---------------- phase 1 ----------------
        s16x8 a23[2][2], a45[2][2];
#pragma unroll
        for (int fr = 0; fr < 2; ++fr)
#pragma unroll
            for (int kh = 0; kh < 2; ++kh) {
                a23[fr][kh] = ldsr(Ab, arow0 + (2 + fr) * 16, kh, quad);
                a45[fr][kh] = ldsr(Ab, arow0 + (4 + fr) * 16, kh, quad);
            }
        if (T + 1 < NT) stage_half<FN>(A, m0 + 128, k1, nbuf + ABOFF + 8192);
        SBAR();
        __builtin_amdgcn_s_setprio(1);
#pragma unroll
        for (int fr = 0; fr < 2; ++fr)
#pragma unroll
            for (int fc = 0; fc < FN; ++fc)
#pragma unroll
                for (int kh = 0; kh < 2; ++kh)
                    acc[2 + fr][fc] = __builtin_amdgcn_mfma_f32_16x16x32_bf16(
                        a23[fr][kh], b[fc][kh], acc[2 + fr][fc], 0, 0, 0);
        __builtin_amdgcn_s_setprio(0);
        SBAR();

        // ---------------- phase 2 ----------------
        s16x8 a67[2][2];
#pragma unroll
        for (int fr = 0; fr < 2; ++fr)
#pragma unroll
            for (int kh = 0; kh < 2; ++kh)
                a67[fr][kh] = ldsr(Ab, arow0 + (6 + fr) * 16, kh, quad);
        if (T + 2 < NT) stage_half<FN>(Bt, c0, k2, buf);
        SBAR();
        __builtin_amdgcn_s_setprio(1);
#pragma unroll
        for (int fr = 0; fr < 2; ++fr)
#pragma unroll
            for (int fc = 0; fc < FN; ++fc)
#pragma unroll
                for (int kh = 0; kh < 2; ++kh)
                    acc[4 + fr][fc] = __builtin_amdgcn_mfma_f32_16x16x32_bf16(
                        a45[fr][kh], b[fc][kh], acc[4 + fr][fc], 0, 0, 0);
        __builtin_amdgcn_s_setprio(0);
        SBAR();

        // ---------------- phase 3 ----------------
        if constexpr (FN == 4) {
            if (T + 2 < NT) stage_half<FN>(Bt, c0 + 128, k2, buf + 8192);
        }
        __builtin_amdgcn_sched_barrier(0);
        if (T <= NT - 3) {
            if constexpr (FN == 4) asm volatile("s_waitcnt vmcnt(4)" ::: "memory");
            else                   asm volatile("s_waitcnt vmcnt(2)" ::: "memory");
        } else if (T == NT - 2) {
            asm volatile("s_waitcnt vmcnt(0)" ::: "memory");
        }
        SBAR();
        __builtin_amdgcn_s_setprio(1);
#pragma unroll
        for (int fr = 0; fr < 2; ++fr)
#pragma unroll
            for (int fc = 0; fc < FN; ++fc)
#pragma unroll
                for (int kh = 0; kh < 2; ++kh)
                    acc[6 + fr][fc] = __builtin_amdgcn_mfma_f32_16x16x32_bf16(
                        a67[fr][kh], b[fc][kh], acc[6 + fr][fc], 0, 0, 0);
        __builtin_amdgcn_s_setprio(0);
        SBAR();
    }
}

// ---------------------------------------------------------------------------
// Fused QKV GEMM, 256x256 8-phase. Grid 12x16 = 192 wgs, XCD-swizzled.
// ---------------------------------------------------------------------------
__global__ __launch_bounds__(512, 2) void gemm_qkv(
    const unsigned short* __restrict__ Ah,
    const unsigned short* __restrict__ Wqt,
    const unsigned short* __restrict__ Wkt,
    const unsigned short* __restrict__ Wvt,
    unsigned short* __restrict__ Qb,
    unsigned short* __restrict__ Kb,
    unsigned short* __restrict__ Vb)
{
    __shared__ __align__(16) unsigned short lds[2 * 4 * 8192];   // 128 KiB
    const int id  = blockIdx.y * 12 + blockIdx.x;     // 0..191
    const int swz = (id & 7) * 24 + (id >> 3);        // XCD-contiguous chunks
    const int nblk = (swz % 12) * 256;                // 0..2815 over [Q|K|V]
    const int m0   = (swz / 12) * 256;
    const unsigned short* Bt;
    unsigned short* C;
    int c0, ldc;
    if (nblk < QW)            { Bt = Wqt; C = Qb; c0 = nblk;            ldc = QW;  }
    else if (nblk < QW + KVW) { Bt = Wkt; C = Kb; c0 = nblk - QW;       ldc = KVW; }
    else                      { Bt = Wvt; C = Vb; c0 = nblk - QW - KVW; ldc = KVW; }

    f32x4 acc[8][4];
    gemm8p<4>(Ah, Bt, m0, c0, lds, acc);

    const int tid = threadIdx.x;
    const int lane = tid & 63;
    const int quad = lane >> 4, l15 = lane & 15;
    const int wm = (tid >> 6) >> 2, wn = (tid >> 6) & 3;
#pragma unroll
    for (int fr = 0; fr < 8; ++fr)
#pragma unroll
        for (int fc = 0; fc < 4; ++fc)
#pragma unroll
            for (int r = 0; r < 4; ++r) {
                int row = m0 + wm * 128 + fr * 16 + quad * 4 + r;   // m89 C/D layout
                int col = c0 + wn * 64 + fc * 16 + l15;
                C[(size_t)row * ldc + col] = f2b(acc[fr][fc][r]);
            }
}

// ---------------------------------------------------------------------------
// Out-projection GEMM, 256x128 8-phase. Grid 16x16 = 256 wgs (1/CU),
// XCD-swizzled, fp32 output.
// ---------------------------------------------------------------------------
__global__ __launch_bounds__(512, 2) void gemm_out(
    const unsigned short* __restrict__ ctx,
    const unsigned short* __restrict__ Wot,
    float* __restrict__ out)
{
    __shared__ __align__(16) unsigned short lds[2 * 3 * 8192];   // 96 KiB
    const int id  = blockIdx.y * 16 + blockIdx.x;     // 0..255
    const int swz = (id & 7) * 32 + (id >> 3);        // XCD-contiguous chunks
    const int c0 = (swz & 15) * 128;
    const int m0 = (swz >> 4) * 256;

    f32x4 acc[8][2];
    gemm8p<2>(ctx, Wot, m0, c0, lds, acc);

    const int tid = threadIdx.x;
    const int lane = tid & 63;
    const int quad = lane >> 4, l15 = lane & 15;
    const int wm = (tid >> 6) >> 2, wn = (tid >> 6) & 3;
#pragma unroll
    for (int fr = 0; fr < 8; ++fr)
#pragma unroll
        for (int fc = 0; fc < 2; ++fc)
#pragma unroll
            for (int r = 0; r < 4; ++r) {
                int row = m0 + wm * 128 + fr * 16 + quad * 4 + r;
                int col = c0 + wn * 32 + fc * 16 + l15;
                out[(size_t)row * HH + col] = acc[fr][fc][r];
            }
}

// ---------------------------------------------------------------------------
// prep: hidden fp32->bf16 convert + all four weight transposes, ONE launch.
// ---------------------------------------------------------------------------
__global__ __launch_bounds__(256) void prep(
    const float* __restrict__ hidden, unsigned short* __restrict__ Ah,
    const float* __restrict__ Wq, const float* __restrict__ Wk,
    const float* __restrict__ Wv, const float* __restrict__ Wo,
    unsigned short* __restrict__ Wqt, unsigned short* __restrict__ Wkt,
    unsigned short* __restrict__ Wvt, unsigned short* __restrict__ Wot)
{
    __shared__ float t[32][33];
    const int bx = blockIdx.x;
    if (bx < 8192) {
        int i = (bx * 256 + threadIdx.x) * 4;
        float4 v = *(const float4*)(hidden + i);
        ushort4 o = make_ushort4(f2b(v.x), f2b(v.y), f2b(v.z), f2b(v.w));
        *(ushort4*)(Ah + i) = o;
        return;
    }
    const int b2 = bx - 8192;
    const int z  = b2 >> 12;
    const int xy = b2 & 4095;
    const float* in;
    unsigned short* out;
    int N;
    if (z == 0)      { in = Wq; out = Wqt; N = QW;  }
    else if (z == 1) { in = Wk; out = Wkt; N = KVW; }
    else if (z == 2) { in = Wv; out = Wvt; N = KVW; }
    else             { in = Wo; out = Wot; N = HH;  }
    const int n0 = (xy & 63) * 32;
    if (n0 >= N) return;
    const int k0 = (xy >> 6) * 32;

    const int c = threadIdx.x & 31, r = threadIdx.x >> 5;   // r = 0..7
#pragma unroll
    for (int j = 0; j < 4; ++j)
        t[r + j * 8][c] = in[(size_t)(k0 + r + j * 8) * N + n0 + c];
    __syncthreads();
#pragma unroll
    for (int j = 0; j < 4; ++j)
        out[(size_t)(n0 + r + j * 8) * HH + k0 + c] = f2b(t[c][r + j * 8]);
}

// bf16 V [b*SS+s][KVW] -> V^T [b*KVW + c][SS]  (per-batch transpose)
__global__ __launch_bounds__(256) void vtrans_bf16(const unsigned short* __restrict__ Vb,
                                                   unsigned short* __restrict__ Vtg)
{
    __shared__ unsigned short t[32][33];
    const int s0 = blockIdx.x * 32, c0 = blockIdx.y * 32, b = blockIdx.z;
    const int cc = threadIdx.x & 31, r = threadIdx.x >> 5;   // r = 0..7
#pragma unroll
    for (int j = 0; j < 4; ++j)
        t[r + j * 8][cc] = Vb[(size_t)(b * SS + s0 + r + j * 8) * KVW + c0 + cc];
    __syncthreads();
#pragma unroll
    for (int j = 0; j < 4; ++j)
        Vtg[(size_t)(b * KVW + c0 + r + j * 8) * SS + s0 + cc] = t[cc][r + j * 8];
}

// ---------------------------------------------------------------------------
// RoPE on Q and K, vectorized x8. Scale folded into Q.
// ---------------------------------------------------------------------------
__global__ __launch_bounds__(256) void rope_all(unsigned short* __restrict__ Qb,
                                                unsigned short* __restrict__ Kb)
{
    int idx = blockIdx.x * 256 + threadIdx.x;
    const int totalQ = BSZ * NH * 8;
    unsigned short* X;
    int nheads; float mul;
    if (idx < totalQ) { X = Qb; nheads = NH; mul = 0.08838834764831845f; }
    else              { X = Kb; nheads = KVH; mul = 1.0f; idx -= totalQ; }
    const int j0 = (idx & 7) * 8;
    const int t  = idx >> 3;
    const int hh = t % nheads;
    const int bs = t / nheads;
    const float s = (float)(bs & (SS - 1));
    size_t base = (size_t)bs * ((size_t)nheads * HD) + (size_t)hh * HD + j0;
    s16x8 v1 = *(const s16x8*)(X + base);
    s16x8 v2 = *(const s16x8*)(X + base + 64);
    s16x8 o1, o2;
#pragma unroll
    for (int e = 0; e < 8; ++e) {
        // 10000^(-j/64) = 2^(-j*log2(10000)/64)
        float inv = exp2f(-0.2076205063f * (float)(j0 + e));
        float ang = s * inv;
        float c = __cosf(ang), sn = __sinf(ang);
        float x1 = b2f((unsigned short)v1[e]);
        float x2 = b2f((unsigned short)v2[e]);
        o1[e] = (short)f2b((x1 * c - x2 * sn) * mul);
        o2[e] = (short)f2b((x2 * c + x1 * sn) * mul);
    }
    *(s16x8*)(X + base)      = o1;
    *(s16x8*)(X + base + 64) = o2;
}

// ---------------------------------------------------------------------------
// Flash attention, bf16 MFMA, PARALLEL causal pairing (R8 structure, spill
// fixed): each block owns q-tiles p and 31-p, processed per shared staged
// k-tile — tile-b every kt, tile-a for kt <= p. Per-block COMPUTE = 33
// k-tile units, exactly uniform over 512 blocks; staging (32-p tiles)
// hides under compute. Two independent MFMA/softmax chains per wave per
// staged tile = 2x per-wave ILP at the same 8 waves/CU (R9's diagnosis:
// 40 us of latency stall at 2 waves/SIMD).
// R8's 187 us came SOLELY from __launch_bounds__(256,2) capping VGPR at
// 128 -> 352 MB scratch spill. Fix: no min-waves clamp; compiler takes
// ~180 VGPR = 2 waves/SIMD, which exactly matches the grid-limited 2
// blocks/CU — no occupancy loss, no spill.
// Fixed-max softmax (P=exp(s-10), exact) keeps tiles independent.
// ---------------------------------------------------------------------------
__global__ __launch_bounds__(256) void attn_mfma(
    const unsigned short* __restrict__ Qb,
    const unsigned short* __restrict__ Kb,
    const unsigned short* __restrict__ Vtg,
    unsigned short* __restrict__ ctx)
{
    const int b   = blockIdx.x;          // 0..1
    const int h   = blockIdx.y;          // 0..15
    const int p   = blockIdx.z;          // 0..15 pair index
    const int kvh = h >> 2;
    const int q0a = p * 64;              // small tile: active kt <= p
    const int q0b = (31 - p) * 64;       // large tile: active all kt
    const int tid = threadIdx.x;
    const int lane = tid & 63, wave = tid >> 6;
    const int quad = lane >> 4, l15 = lane & 15;
    const int lo8 = l15 & 7, hi8 = l15 >> 3;

    __shared__ __align__(16) unsigned short Ks[64 * 128];   // 16 KiB, swizzled
    __shared__ __align__(16) unsigned short Vt[128 * 64];   // 16 KiB, swizzled
    __shared__ __align__(16) unsigned short Ps[4][16 * 64]; //  8 KiB, swizzled, wave-private

    // staging thread->element maps (fixed across u)
    const int krb = tid >> 4;            // 0..15 (K row base within 16-chunk)
    const int c8k = tid & 15;            // K 16B-block col
    const int dv  = tid >> 3;            // 0..31 (V^T d base within 32-chunk)
    const int c8v = tid & 7;             // V^T 16B-block col

    const unsigned short* Kbase = Kb  + (size_t)b * SS * KVW + kvh * HD;
    const unsigned short* Vbase = Vtg + (size_t)(b * KVW + kvh * HD) * SS;

    // Q A-frags for both tiles: 16 rows/wave x 4 d-chunks each
    s16x8 qfa[4], qfb[4];
    {
        const unsigned short* qra =
            Qb + (size_t)(b * SS + q0a + wave * 16 + l15) * QW + h * HD;
        const unsigned short* qrb =
            Qb + (size_t)(b * SS + q0b + wave * 16 + l15) * QW + h * HD;
#pragma unroll
        for (int dc = 0; dc < 4; ++dc) {
            qfa[dc] = *(const s16x8*)(qra + dc * 32 + quad * 8);
            qfb[dc] = *(const s16x8*)(qrb + dc * 32 + quad * 8);
        }
    }

    f32x4 oacca[8], oaccb[8];
#pragma unroll
    for (int i = 0; i < 8; ++i) {
        oacca[i] = (f32x4){0.f, 0.f, 0.f, 0.f};
        oaccb[i] = (f32x4){0.f, 0.f, 0.f, 0.f};
    }
    f32x4 lacca = (f32x4){0.f, 0.f, 0.f, 0.f};
    f32x4 laccb = (f32x4){0.f, 0.f, 0.f, 0.f};

    const s16x8 vone = {0x3F80, 0x3F80, 0x3F80, 0x3F80,
                        0x3F80, 0x3F80, 0x3F80, 0x3F80};   // bf16 1.0 x8

    // one k-tile step for one q-tile (QK^T -> softmax -> P LDS -> PV + l)
    auto tile_step = [&](const s16x8 (&qf)[4], f32x4 (&oacc)[8],
                         f32x4& lacc, bool lastt) {
        f32x4 sc[4];
#pragma unroll
        for (int tk = 0; tk < 4; ++tk) sc[tk] = (f32x4){0.f, 0.f, 0.f, 0.f};
        __builtin_amdgcn_s_setprio(1);
#pragma unroll
        for (int tk = 0; tk < 4; ++tk) {
#pragma unroll
            for (int dc = 0; dc < 4; ++dc) {
                s16x8 kf = *(const s16x8*)(Ks + (tk * 16 + l15) * 128
                                              + (((dc * 4 + quad) ^ l15) * 8));
                sc[tk] = __builtin_amdgcn_mfma_f32_16x16x32_bf16(qf[dc], kf, sc[tk], 0, 0, 0);
            }
        }
        __builtin_amdgcn_s_setprio(0);

        // fixed-max softmax: P = exp(s - 10), exact; masked -> 0 on the
        // (unique) diagonal tile, where k0 == q0 of THIS q-tile.
        unsigned short* pw = &Ps[wave][0];
#pragma unroll
        for (int tk = 0; tk < 4; ++tk) {
            float pv[4];
#pragma unroll
            for (int r = 0; r < 4; ++r)
                pv[r] = __expf(sc[tk][r] - 10.0f);
            if (lastt) {
                const int colr = tk * 16 + l15 - wave * 16 - quad * 4;  // mask iff colr > r
#pragma unroll
                for (int r = 0; r < 4; ++r)
                    if (colr > r) pv[r] = 0.f;
            }
            const int cb = tk * 2 + hi8;              // 16B-block col 0..7
            const int row0 = quad * 4;
#pragma unroll
            for (int r = 0; r < 4; ++r)
                pw[(row0 + r) * 64 + (((cb ^ ((row0 + r) & 7)) << 3) | lo8)] = f2b(pv[r]);
        }

        // PV + l: pf (A-layout) from wave-private swizzled LDS (no barrier:
        // within-wave DS ordering)
        s16x8 pf[2];
#pragma unroll
        for (int kc = 0; kc < 2; ++kc)
            pf[kc] = *(const s16x8*)(pw + l15 * 64 + (((kc * 4 + quad) ^ lo8) << 3));
        __builtin_amdgcn_s_setprio(1);
        lacc = __builtin_amdgcn_mfma_f32_16x16x32_bf16(pf[0], vone, lacc, 0, 0, 0);
        lacc = __builtin_amdgcn_mfma_f32_16x16x32_bf16(pf[1], vone, lacc, 0, 0, 0);
#pragma unroll
        for (int dt = 0; dt < 8; ++dt) {
#pragma unroll
            for (int kc = 0; kc < 2; ++kc) {
                s16x8 vf = *(const s16x8*)(Vt + (dt * 16 + l15) * 64
                                              + (((kc * 4 + quad) ^ lo8) * 8));
                oacc[dt] = __builtin_amdgcn_mfma_f32_16x16x32_bf16(pf[kc], vf, oacc[dt], 0, 0, 0);
            }
        }
        __builtin_amdgcn_s_setprio(0);
    };

    // prefetch registers: 4 K chunks + 4 V chunks (16B each)
    s16x8 kpre[4], vpre[4];
#pragma unroll
    for (int u = 0; u < 4; ++u) {
        kpre[u] = *(const s16x8*)(Kbase + (size_t)(u * 16 + krb) * KVW + c8k * 8);
        vpre[u] = *(const s16x8*)(Vbase + (size_t)(u * 32 + dv) * SS + c8v * 8);
    }

    const int nkt = 32 - p;              // tile-b's k-range (covers tile-a's)
    for (int kt = 0; kt < nkt; ++kt) {
        const int k0 = kt * 64;
        __syncthreads();   // previous iteration's Ks/Vt readers done

        // store prefetched tile (compiler inserts vmcnt wait here)
#pragma unroll
        for (int u = 0; u < 4; ++u) {
            *(s16x8*)(Ks + (u * 16 + krb) * 128 + ((c8k ^ krb) * 8)) = kpre[u];
            *(s16x8*)(Vt + (u * 32 + dv) * 64 + ((c8v ^ (dv & 7)) * 8)) = vpre[u];
        }
        __syncthreads();

        // issue next tile's global loads (latency hides behind compute)
        if (kt + 1 < nkt) {
            const int kn = k0 + 64;
#pragma unroll
            for (int u = 0; u < 4; ++u) {
                kpre[u] = *(const s16x8*)(Kbase + (size_t)(kn + u * 16 + krb) * KVW + c8k * 8);
                vpre[u] = *(const s16x8*)(Vbase + (size_t)(u * 32 + dv) * SS + kn + c8v * 8);
            }
        }

        // large tile: every kt; its diagonal is the last kt (k0 == q0b)
        tile_step(qfb, oaccb, laccb, kt == nkt - 1);
        // small tile: shares the staged K/V prefix; diagonal at kt == p
        if (kt <= p)
            tile_step(qfa, oacca, lacca, kt == p);
    }

    // epilogue: O / l for both tiles
    auto write_out = [&](const f32x4 (&oacc)[8], const f32x4& lacc, int q0) {
        float linv[4];
#pragma unroll
        for (int r = 0; r < 4; ++r) linv[r] = 1.0f / lacc[r];
#pragma unroll
        for (int dt = 0; dt < 8; ++dt)
#pragma unroll
            for (int r = 0; r < 4; ++r) {
                int row = b * SS + q0 + wave * 16 + quad * 4 + r;
                ctx[(size_t)row * QW + h * HD + dt * 16 + l15] =
                    f2b(oacc[dt][r] * linv[r]);
            }
    };
    write_out(oacca, lacca, q0a);
    write_out(oaccb, laccb, q0b);
}

// ---------------------------------------------------------------------------
extern "C" void kernel_launch(void* const* d_in, const int* in_sizes, int n_in,
                              void* d_out, int out_size, void* d_ws, size_t ws_size,
                              hipStream_t stream)
{
    const float* hidden = (const float*)d_in[0];
    const float* Wq = (const float*)d_in[1];
    const float* Wk = (const float*)d_in[2];
    const float* Wv = (const float*)d_in[3];
    const float* Wo = (const float*)d_in[4];
    float* out = (float*)d_out;

    // workspace layout (bf16 elements)
    unsigned short* Ah  = (unsigned short*)d_ws;                 // 4096*2048
    unsigned short* Wqt = Ah  + (size_t)BSZ * HH;                // 2048*2048
    unsigned short* Wkt = Wqt + (size_t)QW * HH;                 // 512*2048
    unsigned short* Wvt = Wkt + (size_t)KVW * HH;                // 512*2048
    unsigned short* Wot = Wvt + (size_t)KVW * HH;                // 2048*2048
    unsigned short* Qb  = Wot + (size_t)HH * QW;                 // 4096*2048
    unsigned short* Kb  = Qb  + (size_t)BSZ * QW;                // 4096*512
    unsigned short* Vb  = Kb  + (size_t)BSZ * KVW;               // 4096*512
    unsigned short* ctx = Vb  + (size_t)BSZ * KVW;               // 4096*2048
    unsigned short* Vtg = ctx + (size_t)BSZ * QW;                // 4096*512 (V^T)

    // 1. conversions + weight transposes (single launch)
    prep<<<24576, 256, 0, stream>>>(hidden, Ah, Wq, Wk, Wv, Wo,
                                    Wqt, Wkt, Wvt, Wot);

    // 2. fused QKV GEMM (8-phase 256x256, counted vmcnt), XCD-swizzled
    gemm_qkv<<<dim3(12, 16), 512, 0, stream>>>(Ah, Wqt, Wkt, Wvt, Qb, Kb, Vb);

    // 3. V^T for attention's PV B-operand (s-contiguous rows)
    vtrans_bf16<<<dim3(SS / 32, KVW / 32, BB), 256, 0, stream>>>(Vb, Vtg);

    // 4. RoPE on Q and K (scale folded into Q), vectorized x8
    rope_all<<<(BSZ * (NH + KVH) * 8) / 256, 256, 0, stream>>>(Qb, Kb);

    // 5. flash attention, parallel causal pairing (no VGPR clamp): 512 blocks
    attn_mfma<<<dim3(BB, NH, 16), 256, 0, stream>>>(Qb, Kb, Vtg, ctx);

    // 6. out-projection (8-phase 256x128, perfect 256-block fill), XCD-swizzled
    gemm_out<<<dim3(16, 16), 512, 0, stream>>>(ctx, Wot, out);
}

// Round 11
// 271.480 us; speedup vs baseline: 1.0842x; 1.0842x over previous
//
#include <hip/hip_runtime.h>
#include <stdint.h>
#include <math.h>

#define BB 2
#define SS 2048
#define HH 2048
#define NH 16
#define KVH 4
#define HD 128
#define BSZ (BB*SS)      // 4096
#define QW (NH*HD)       // 2048
#define KVW (KVH*HD)     // 512

typedef __attribute__((ext_vector_type(8))) short s16x8;   // 8 bf16 = 4 VGPRs
typedef __attribute__((ext_vector_type(4))) float f32x4;   // MFMA C/D

typedef const unsigned int __attribute__((address_space(1)))* gas_ptr;
typedef unsigned int __attribute__((address_space(3)))* las_ptr;

__device__ __forceinline__ unsigned short f2b(float x) {
    unsigned u = __builtin_bit_cast(unsigned, x);
    unsigned r = u + 0x7fffu + ((u >> 16) & 1u);   // round-to-nearest-even
    return (unsigned short)(r >> 16);
}
__device__ __forceinline__ float b2f(unsigned short h) {
    unsigned u = ((unsigned)h) << 16;
    return __builtin_bit_cast(float, u);
}

// async global->LDS, 16B per lane; LDS dest = wave-uniform base + lane*16
__device__ __forceinline__ void gload_lds16(const void* g, void* l) {
    __builtin_amdgcn_global_load_lds((gas_ptr)g, (las_ptr)l, 16, 0, 0);
}

// ===========================================================================
// True 8-phase GEMM (m201-style), BK=64, double-buffered, counted vmcnt.
// (verified R7: 294->273 µs)
// ===========================================================================
template<int FN>
__device__ __forceinline__ void stage_half(
    const unsigned short* __restrict__ src, int rowbase, int k0,
    unsigned short* dst)
{
    const int tid = threadIdx.x;
#pragma unroll
    for (int q = 0; q < 2; ++q) {
        int row = (tid >> 3) + q * 64;
        int sl  = (tid & 7) ^ (row & 7);
        gload_lds16(src + (size_t)(rowbase + row) * HH + k0 + sl * 8,
                    dst + (q * 512 + tid) * 8);
    }
}

__device__ __forceinline__ s16x8 ldsr(const unsigned short* base,
                                      int r, int kh, int quad)
{
    return *(const s16x8*)(base + r * 64 + (((kh * 4 + quad) ^ (r & 7)) * 8));
}

#define SBAR() do { __builtin_amdgcn_sched_barrier(0); \
                    __builtin_amdgcn_s_barrier();       \
                    __builtin_amdgcn_sched_barrier(0); } while (0)

template<int FN>
__device__ __forceinline__ void gemm8p(
    const unsigned short* __restrict__ A,
    const unsigned short* __restrict__ Bt,
    int m0, int c0, unsigned short* lds, f32x4 acc[8][FN])
{
    constexpr int NT    = HH / 64;            // 32 K-tiles
    constexpr int BUFE  = (2 + FN / 2) * 8192;
    constexpr int ABOFF = (FN / 2) * 8192;    // A region start (elements)
    const int tid  = threadIdx.x;
    const int lane = tid & 63, wave = tid >> 6;
    const int quad = lane >> 4, l15 = lane & 15;
    const int wm = wave >> 2, wn = wave & 3;
    const int arow0 = wm * 128 + l15;         // + fr*16
    const int brow0 = wn * (FN * 16) + l15;   // + fc*16

#pragma unroll
    for (int i = 0; i < 8; ++i)
#pragma unroll
        for (int fc = 0; fc < FN; ++fc) acc[i][fc] = (f32x4){0.f, 0.f, 0.f, 0.f};

    unsigned short* buf0 = lds;
    unsigned short* buf1 = lds + BUFE;

    // ---- prologue: B(0)[,B-hi(0)], A-lo(0), A-hi(0), B(1)[,B-hi(1)] ----
    stage_half<FN>(Bt, c0, 0, buf0);
    if constexpr (FN == 4) stage_half<FN>(Bt, c0 + 128, 0, buf0 + 8192);
    stage_half<FN>(A, m0, 0, buf0 + ABOFF);
    stage_half<FN>(A, m0 + 128, 0, buf0 + ABOFF + 8192);
    stage_half<FN>(Bt, c0, 64, buf1);
    if constexpr (FN == 4) {
        stage_half<FN>(Bt, c0 + 128, 64, buf1 + 8192);
        asm volatile("s_waitcnt vmcnt(4)" ::: "memory");  // tile 0 landed
    } else {
        asm volatile("s_waitcnt vmcnt(2)" ::: "memory");
    }
    SBAR();

#pragma unroll 2
    for (int T = 0; T < NT; ++T) {
        unsigned short* buf = (T & 1) ? buf1 : buf0;
        unsigned short* nbuf = (T & 1) ? buf0 : buf1;   // T+1 -> nbuf, T+2 -> buf
        const unsigned short* Bb = buf;
        const unsigned short* Ab = buf + ABOFF;
        const int k1 = (T + 1) * 64, k2 = (T + 2) * 64;

        // ---------------- phase 0 ----------------
        s16x8 b[FN][2], a01[2][2];
#pragma unroll
        for (int fc = 0; fc < FN; ++fc)
#pragma unroll
            for (int kh = 0; kh < 2; ++kh)
                b[fc][kh] = ldsr(Bb, brow0 + fc * 16, kh, quad);
#pragma unroll
        for (int fr = 0; fr < 2; ++fr)
#pragma unroll
            for (int kh = 0; kh < 2; ++kh)
                a01[fr][kh] = ldsr(Ab, arow0 + fr * 16, kh, quad);
        if (T + 1 < NT) stage_half<FN>(A, m0, k1, nbuf + ABOFF);
        SBAR();
        __builtin_amdgcn_s_setprio(1);
#pragma unroll
        for (int fr = 0; fr < 2; ++fr)
#pragma unroll
            for (int fc = 0; fc < FN; ++fc)
#pragma unroll
                for (int kh = 0; kh < 2; ++kh)
                    acc[fr][fc] = __builtin_amdgcn_mfma_f32_16x16x32_bf16(
                        a01[fr][kh], b[fc][kh], acc[fr][fc], 0, 0, 0);
        __builtin_amdgcn_s_setprio(0);
        SBAR();

        // ---------------- phase 1 ----------------
        s16x8 a23[2][2], a45[2][2];
#pragma unroll
        for (int fr = 0; fr < 2; ++fr)
#pragma unroll
            for (int kh = 0; kh < 2; ++kh) {
                a23[fr][kh] = ldsr(Ab, arow0 + (2 + fr) * 16, kh, quad);
                a45[fr][kh] = ldsr(Ab, arow0 + (4 + fr) * 16, kh, quad);
            }
        if (T + 1 < NT) stage_half<FN>(A, m0 + 128, k1, nbuf + ABOFF + 8192);
        SBAR();
        __builtin_amdgcn_s_setprio(1);
#pragma unroll
        for (int fr = 0; fr < 2; ++fr)
#pragma unroll
            for (int fc = 0; fc < FN; ++fc)
#pragma unroll
                for (int kh = 0; kh < 2; ++kh)
                    acc[2 + fr][fc] = __builtin_amdgcn_mfma_f32_16x16x32_bf16(
                        a23[fr][kh], b[fc][kh], acc[2 + fr][fc], 0, 0, 0);
        __builtin_amdgcn_s_setprio(0);
        SBAR();

        // ---------------- phase 2 ----------------
        s16x8 a67[2][2];
#pragma unroll
        for (int fr = 0; fr < 2; ++fr)
#pragma unroll
            for (int kh = 0; kh < 2; ++kh)
                a67[fr][kh] = ldsr(Ab, arow0 + (6 + fr) * 16, kh, quad);
        if (T + 2 < NT) stage_half<FN>(Bt, c0, k2, buf);
        SBAR();
        __builtin_amdgcn_s_setprio(1);
#pragma unroll
        for (int fr = 0; fr < 2; ++fr)
#pragma unroll
            for (int fc = 0; fc < FN; ++fc)
#pragma unroll
                for (int kh = 0; kh < 2; ++kh)
                    acc[4 + fr][fc] = __builtin_amdgcn_mfma_f32_16x16x32_bf16(
                        a45[fr][kh], b[fc][kh], acc[4 + fr][fc], 0, 0, 0);
        __builtin_amdgcn_s_setprio(0);
        SBAR();

        // ---------------- phase 3 ----------------
        if constexpr (FN == 4) {
            if (T + 2 < NT) stage_half<FN>(Bt, c0 + 128, k2, buf + 8192);
        }
        __builtin_amdgcn_sched_barrier(0);
        if (T <= NT - 3) {
            if constexpr (FN == 4) asm volatile("s_waitcnt vmcnt(4)" ::: "memory");
            else                   asm volatile("s_waitcnt vmcnt(2)" ::: "memory");
        } else if (T == NT - 2) {
            asm volatile("s_waitcnt vmcnt(0)" ::: "memory");
        }
        SBAR();
        __builtin_amdgcn_s_setprio(1);
#pragma unroll
        for (int fr = 0; fr < 2; ++fr)
#pragma unroll
            for (int fc = 0; fc < FN; ++fc)
#pragma unroll
                for (int kh = 0; kh < 2; ++kh)
                    acc[6 + fr][fc] = __builtin_amdgcn_mfma_f32_16x16x32_bf16(
                        a67[fr][kh], b[fc][kh], acc[6 + fr][fc], 0, 0, 0);
        __builtin_amdgcn_s_setprio(0);
        SBAR();
    }
}

// ---------------------------------------------------------------------------
// Fused QKV GEMM, 256x256 8-phase. Grid 12x16 = 192 wgs, XCD-swizzled.
// ---------------------------------------------------------------------------
__global__ __launch_bounds__(512, 2) void gemm_qkv(
    const unsigned short* __restrict__ Ah,
    const unsigned short* __restrict__ Wqt,
    const unsigned short* __restrict__ Wkt,
    const unsigned short* __restrict__ Wvt,
    unsigned short* __restrict__ Qb,
    unsigned short* __restrict__ Kb,
    unsigned short* __restrict__ Vb)
{
    __shared__ __align__(16) unsigned short lds[2 * 4 * 8192];   // 128 KiB
    const int id  = blockIdx.y * 12 + blockIdx.x;     // 0..191
    const int swz = (id & 7) * 24 + (id >> 3);        // XCD-contiguous chunks
    const int nblk = (swz % 12) * 256;                // 0..2815 over [Q|K|V]
    const int m0   = (swz / 12) * 256;
    const unsigned short* Bt;
    unsigned short* C;
    int c0, ldc;
    if (nblk < QW)            { Bt = Wqt; C = Qb; c0 = nblk;            ldc = QW;  }
    else if (nblk < QW + KVW) { Bt = Wkt; C = Kb; c0 = nblk - QW;       ldc = KVW; }
    else                      { Bt = Wvt; C = Vb; c0 = nblk - QW - KVW; ldc = KVW; }

    f32x4 acc[8][4];
    gemm8p<4>(Ah, Bt, m0, c0, lds, acc);

    const int tid = threadIdx.x;
    const int lane = tid & 63;
    const int quad = lane >> 4, l15 = lane & 15;
    const int wm = (tid >> 6) >> 2, wn = (tid >> 6) & 3;
#pragma unroll
    for (int fr = 0; fr < 8; ++fr)
#pragma unroll
        for (int fc = 0; fc < 4; ++fc)
#pragma unroll
            for (int r = 0; r < 4; ++r) {
                int row = m0 + wm * 128 + fr * 16 + quad * 4 + r;   // m89 C/D layout
                int col = c0 + wn * 64 + fc * 16 + l15;
                C[(size_t)row * ldc + col] = f2b(acc[fr][fc][r]);
            }
}

// ---------------------------------------------------------------------------
// Out-projection GEMM, 256x128 8-phase. Grid 16x16 = 256 wgs (1/CU),
// XCD-swizzled, fp32 output.
// ---------------------------------------------------------------------------
__global__ __launch_bounds__(512, 2) void gemm_out(
    const unsigned short* __restrict__ ctx,
    const unsigned short* __restrict__ Wot,
    float* __restrict__ out)
{
    __shared__ __align__(16) unsigned short lds[2 * 3 * 8192];   // 96 KiB
    const int id  = blockIdx.y * 16 + blockIdx.x;     // 0..255
    const int swz = (id & 7) * 32 + (id >> 3);        // XCD-contiguous chunks
    const int c0 = (swz & 15) * 128;
    const int m0 = (swz >> 4) * 256;

    f32x4 acc[8][2];
    gemm8p<2>(ctx, Wot, m0, c0, lds, acc);

    const int tid = threadIdx.x;
    const int lane = tid & 63;
    const int quad = lane >> 4, l15 = lane & 15;
    const int wm = (tid >> 6) >> 2, wn = (tid >> 6) & 3;
#pragma unroll
    for (int fr = 0; fr < 8; ++fr)
#pragma unroll
        for (int fc = 0; fc < 2; ++fc)
#pragma unroll
            for (int r = 0; r < 4; ++r) {
                int row = m0 + wm * 128 + fr * 16 + quad * 4 + r;
                int col = c0 + wn * 32 + fc * 16 + l15;
                out[(size_t)row * HH + col] = acc[fr][fc][r];
            }
}

// ---------------------------------------------------------------------------
// prep: hidden fp32->bf16 convert + all four weight transposes, ONE launch.
// ---------------------------------------------------------------------------
__global__ __launch_bounds__(256) void prep(
    const float* __restrict__ hidden, unsigned short* __restrict__ Ah,
    const float* __restrict__ Wq, const float* __restrict__ Wk,
    const float* __restrict__ Wv, const float* __restrict__ Wo,
    unsigned short* __restrict__ Wqt, unsigned short* __restrict__ Wkt,
    unsigned short* __restrict__ Wvt, unsigned short* __restrict__ Wot)
{
    __shared__ float t[32][33];
    const int bx = blockIdx.x;
    if (bx < 8192) {
        int i = (bx * 256 + threadIdx.x) * 4;
        float4 v = *(const float4*)(hidden + i);
        ushort4 o = make_ushort4(f2b(v.x), f2b(v.y), f2b(v.z), f2b(v.w));
        *(ushort4*)(Ah + i) = o;
        return;
    }
    const int b2 = bx - 8192;
    const int z  = b2 >> 12;
    const int xy = b2 & 4095;
    const float* in;
    unsigned short* out;
    int N;
    if (z == 0)      { in = Wq; out = Wqt; N = QW;  }
    else if (z == 1) { in = Wk; out = Wkt; N = KVW; }
    else if (z == 2) { in = Wv; out = Wvt; N = KVW; }
    else             { in = Wo; out = Wot; N = HH;  }
    const int n0 = (xy & 63) * 32;
    if (n0 >= N) return;
    const int k0 = (xy >> 6) * 32;

    const int c = threadIdx.x & 31, r = threadIdx.x >> 5;   // r = 0..7
#pragma unroll
    for (int j = 0; j < 4; ++j)
        t[r + j * 8][c] = in[(size_t)(k0 + r + j * 8) * N + n0 + c];
    __syncthreads();
#pragma unroll
    for (int j = 0; j < 4; ++j)
        out[(size_t)(n0 + r + j * 8) * HH + k0 + c] = f2b(t[c][r + j * 8]);
}

// ---------------------------------------------------------------------------
// vtrope: V transpose + RoPE fused into ONE launch (independent data:
// vtrans reads Vb->Vtg, rope rewrites Qb/Kb in place; both depend only on
// gemm_qkv). blocks [0,2048): vtrans (64 x 16 x 2); [2048,4608): rope.
// ---------------------------------------------------------------------------
__global__ __launch_bounds__(256) void vtrope(
    const unsigned short* __restrict__ Vb, unsigned short* __restrict__ Vtg,
    unsigned short* __restrict__ Qb, unsigned short* __restrict__ Kb)
{
    __shared__ unsigned short t[32][33];
    const int bx = blockIdx.x;
    if (bx < 2048) {
        // --- V transpose: bf16 [b*SS+s][KVW] -> [b*KVW + c][SS] ---
        const int s0 = (bx & 63) * 32;
        const int c0 = ((bx >> 6) & 15) * 32;
        const int b  = bx >> 10;
        const int cc = threadIdx.x & 31, r = threadIdx.x >> 5;   // r = 0..7
#pragma unroll
        for (int j = 0; j < 4; ++j)
            t[r + j * 8][cc] = Vb[(size_t)(b * SS + s0 + r + j * 8) * KVW + c0 + cc];
        __syncthreads();
#pragma unroll
        for (int j = 0; j < 4; ++j)
            Vtg[(size_t)(b * KVW + c0 + r + j * 8) * SS + s0 + cc] = t[cc][r + j * 8];
        return;
    }
    // --- RoPE, vectorized x8; scale 1/sqrt(HD) folded into Q ---
    int idx = (bx - 2048) * 256 + threadIdx.x;
    const int totalQ = BSZ * NH * 8;
    unsigned short* X;
    int nheads; float mul;
    if (idx < totalQ) { X = Qb; nheads = NH; mul = 0.08838834764831845f; }
    else              { X = Kb; nheads = KVH; mul = 1.0f; idx -= totalQ; }
    const int j0 = (idx & 7) * 8;
    const int tt = idx >> 3;
    const int hh = tt % nheads;
    const int bs = tt / nheads;
    const float s = (float)(bs & (SS - 1));
    size_t base = (size_t)bs * ((size_t)nheads * HD) + (size_t)hh * HD + j0;
    s16x8 v1 = *(const s16x8*)(X + base);
    s16x8 v2 = *(const s16x8*)(X + base + 64);
    s16x8 o1, o2;
#pragma unroll
    for (int e = 0; e < 8; ++e) {
        // 10000^(-j/64) = 2^(-j*log2(10000)/64)
        float inv = exp2f(-0.2076205063f * (float)(j0 + e));
        float ang = s * inv;
        float c = __cosf(ang), sn = __sinf(ang);
        float x1 = b2f((unsigned short)v1[e]);
        float x2 = b2f((unsigned short)v2[e]);
        o1[e] = (short)f2b((x1 * c - x2 * sn) * mul);
        o2[e] = (short)f2b((x2 * c + x1 * sn) * mul);
    }
    *(s16x8*)(X + base)      = o1;
    *(s16x8*)(X + base + 64) = o2;
}

// ---------------------------------------------------------------------------
// Flash attention, bf16 MFMA (R7 exact — the verified best: 72 us, VGPR 88,
// 4 blocks/CU, heavy-first LPT). 256 thr = 4 waves; Q-tile 64 rows
// (16/wave), K-tile 64 -> 1024 blocks; LDS 40 KiB. FIXED-max softmax
// (P = exp(s-10), exact). Row-sum l via MFMA ones B-frag. Swizzled K/V/P
// LDS. Register prefetch of tile kt+1. Last-tile-only causal masking.
// T5 s_setprio around MFMA clusters.
// Post-mortem of alternatives (R8/R9/R10): parallel pairing spills (128
// VGPR cap) or under-schedules (184 VGPR, 2 waves/SIMD, occ 10.7%);
// sequential pairing loses the 2x oversubscription. This config wins on
// co-residency: work-starved light blocks drain while heavy blocks keep
// 4-deep block-level overlap per CU.
// ---------------------------------------------------------------------------
__global__ __launch_bounds__(256) void attn_mfma(
    const unsigned short* __restrict__ Qb,
    const unsigned short* __restrict__ Kb,
    const unsigned short* __restrict__ Vtg,
    unsigned short* __restrict__ ctx)
{
    const int b   = blockIdx.x;          // 0..1
    const int h   = blockIdx.y;          // 0..15
    const int qtp = 31 - blockIdx.z;     // heavy first
    const int kvh = h >> 2;
    const int q0  = qtp * 64;
    const int tid = threadIdx.x;
    const int lane = tid & 63, wave = tid >> 6;
    const int quad = lane >> 4, l15 = lane & 15;
    const int lo8 = l15 & 7, hi8 = l15 >> 3;

    __shared__ __align__(16) unsigned short Ks[64 * 128];   // 16 KiB, swizzled
    __shared__ __align__(16) unsigned short Vt[128 * 64];   // 16 KiB, swizzled
    __shared__ __align__(16) unsigned short Ps[4][16 * 64]; //  8 KiB, swizzled, wave-private

    // staging thread->element maps (fixed across u)
    const int krb = tid >> 4;            // 0..15 (K row base within 16-chunk)
    const int c8k = tid & 15;            // K 16B-block col
    const int dv  = tid >> 3;            // 0..31 (V^T d base within 32-chunk)
    const int c8v = tid & 7;             // V^T 16B-block col

    const unsigned short* Kbase = Kb  + (size_t)b * SS * KVW + kvh * HD;
    const unsigned short* Vbase = Vtg + (size_t)(b * KVW + kvh * HD) * SS;

    // Q A-frags: 16 rows/wave x 4 d-chunks
    s16x8 qf[4];
    {
        const unsigned short* qrow =
            Qb + (size_t)(b * SS + q0 + wave * 16 + l15) * QW + h * HD;
#pragma unroll
        for (int dc = 0; dc < 4; ++dc)
            qf[dc] = *(const s16x8*)(qrow + dc * 32 + quad * 8);
    }

    f32x4 oacc[8];
#pragma unroll
    for (int i = 0; i < 8; ++i) oacc[i] = (f32x4){0.f, 0.f, 0.f, 0.f};
    f32x4 lacc = (f32x4){0.f, 0.f, 0.f, 0.f};

    const s16x8 vone = {0x3F80, 0x3F80, 0x3F80, 0x3F80,
                        0x3F80, 0x3F80, 0x3F80, 0x3F80};   // bf16 1.0 x8

    // prefetch registers: 4 K chunks + 4 V chunks (16B each)
    s16x8 kpre[4], vpre[4];
#pragma unroll
    for (int u = 0; u < 4; ++u) {
        kpre[u] = *(const s16x8*)(Kbase + (size_t)(u * 16 + krb) * KVW + c8k * 8);
        vpre[u] = *(const s16x8*)(Vbase + (size_t)(u * 32 + dv) * SS + c8v * 8);
    }

    const int nkt = qtp + 1;
    for (int kt = 0; kt < nkt; ++kt) {
        const int k0 = kt * 64;
        __syncthreads();   // previous iteration's Ks/Vt readers done

        // store prefetched tile (compiler inserts vmcnt wait here)
#pragma unroll
        for (int u = 0; u < 4; ++u) {
            *(s16x8*)(Ks + (u * 16 + krb) * 128 + ((c8k ^ krb) * 8)) = kpre[u];
            *(s16x8*)(Vt + (u * 32 + dv) * 64 + ((c8v ^ (dv & 7)) * 8)) = vpre[u];
        }
        __syncthreads();

        // issue next tile's global loads (latency hides behind compute)
        if (kt + 1 < nkt) {
            const int kn = k0 + 64;
#pragma unroll
            for (int u = 0; u < 4; ++u) {
                kpre[u] = *(const s16x8*)(Kbase + (size_t)(kn + u * 16 + krb) * KVW + c8k * 8);
                vpre[u] = *(const s16x8*)(Vbase + (size_t)(u * 32 + dv) * SS + kn + c8v * 8);
            }
        }

        // S = Q K^T
        f32x4 sc[4];
#pragma unroll
        for (int tk = 0; tk < 4; ++tk) sc[tk] = (f32x4){0.f, 0.f, 0.f, 0.f};
        __builtin_amdgcn_s_setprio(1);
#pragma unroll
        for (int tk = 0; tk < 4; ++tk) {
#pragma unroll
            for (int dc = 0; dc < 4; ++dc) {
                s16x8 kf = *(const s16x8*)(Ks + (tk * 16 + l15) * 128
                                              + (((dc * 4 + quad) ^ l15) * 8));
                sc[tk] = __builtin_amdgcn_mfma_f32_16x16x32_bf16(qf[dc], kf, sc[tk], 0, 0, 0);
            }
        }
        __builtin_amdgcn_s_setprio(0);

        // fixed-max softmax: P = exp(s - 10), exact; masked -> 0.
        // straddle is exactly the last k-tile (k0 == q0 there).
        unsigned short* pw = &Ps[wave][0];
        const bool lastt = (kt == nkt - 1);
#pragma unroll
        for (int tk = 0; tk < 4; ++tk) {
            float p[4];
#pragma unroll
            for (int r = 0; r < 4; ++r)
                p[r] = __expf(sc[tk][r] - 10.0f);
            if (lastt) {
                const int colr = tk * 16 + l15 - wave * 16 - quad * 4;  // mask iff colr > r
#pragma unroll
                for (int r = 0; r < 4; ++r)
                    if (colr > r) p[r] = 0.f;
            }
            const int cb = tk * 2 + hi8;              // 16B-block col 0..7
            const int row0 = quad * 4;
#pragma unroll
            for (int r = 0; r < 4; ++r)
                pw[(row0 + r) * 64 + (((cb ^ ((row0 + r) & 7)) << 3) | lo8)] = f2b(p[r]);
        }

        // PV + l: pf (A-layout) from wave-private swizzled LDS (no barrier:
        // within-wave lgkmcnt ordering).
        s16x8 pf[2];
#pragma unroll
        for (int kc = 0; kc < 2; ++kc)
            pf[kc] = *(const s16x8*)(pw + l15 * 64 + (((kc * 4 + quad) ^ lo8) << 3));
        __builtin_amdgcn_s_setprio(1);
        // l row-sums via ones B-frag (no LDS read)
        lacc = __builtin_amdgcn_mfma_f32_16x16x32_bf16(pf[0], vone, lacc, 0, 0, 0);
        lacc = __builtin_amdgcn_mfma_f32_16x16x32_bf16(pf[1], vone, lacc, 0, 0, 0);
#pragma unroll
        for (int dt = 0; dt < 8; ++dt) {
#pragma unroll
            for (int kc = 0; kc < 2; ++kc) {
                s16x8 vf = *(const s16x8*)(Vt + (dt * 16 + l15) * 64
                                              + (((kc * 4 + quad) ^ lo8) * 8));
                oacc[dt] = __builtin_amdgcn_mfma_f32_16x16x32_bf16(pf[kc], vf, oacc[dt], 0, 0, 0);
            }
        }
        __builtin_amdgcn_s_setprio(0);
    }

    // epilogue: O / l (l in C-layout, same value across cols -> use own lane's)
    float linv[4];
#pragma unroll
    for (int r = 0; r < 4; ++r) linv[r] = 1.0f / lacc[r];
#pragma unroll
    for (int dt = 0; dt < 8; ++dt)
#pragma unroll
        for (int r = 0; r < 4; ++r) {
            int row = b * SS + q0 + wave * 16 + quad * 4 + r;
            ctx[(size_t)row * QW + h * HD + dt * 16 + l15] =
                f2b(oacc[dt][r] * linv[r]);
        }
}

// ---------------------------------------------------------------------------
extern "C" void kernel_launch(void* const* d_in, const int* in_sizes, int n_in,
                              void* d_out, int out_size, void* d_ws, size_t ws_size,
                              hipStream_t stream)
{
    const float* hidden = (const float*)d_in[0];
    const float* Wq = (const float*)d_in[1];
    const float* Wk = (const float*)d_in[2];
    const float* Wv = (const float*)d_in[3];
    const float* Wo = (const float*)d_in[4];
    float* out = (float*)d_out;

    // workspace layout (bf16 elements)
    unsigned short* Ah  = (unsigned short*)d_ws;                 // 4096*2048
    unsigned short* Wqt = Ah  + (size_t)BSZ * HH;                // 2048*2048
    unsigned short* Wkt = Wqt + (size_t)QW * HH;                 // 512*2048
    unsigned short* Wvt = Wkt + (size_t)KVW * HH;                // 512*2048
    unsigned short* Wot = Wvt + (size_t)KVW * HH;                // 2048*2048
    unsigned short* Qb  = Wot + (size_t)HH * QW;                 // 4096*2048
    unsigned short* Kb  = Qb  + (size_t)BSZ * QW;                // 4096*512
    unsigned short* Vb  = Kb  + (size_t)BSZ * KVW;               // 4096*512
    unsigned short* ctx = Vb  + (size_t)BSZ * KVW;               // 4096*2048
    unsigned short* Vtg = ctx + (size_t)BSZ * QW;                // 4096*512 (V^T)

    // 1. conversions + weight transposes (single launch)
    prep<<<24576, 256, 0, stream>>>(hidden, Ah, Wq, Wk, Wv, Wo,
                                    Wqt, Wkt, Wvt, Wot);

    // 2. fused QKV GEMM (8-phase 256x256, counted vmcnt), XCD-swizzled
    gemm_qkv<<<dim3(12, 16), 512, 0, stream>>>(Ah, Wqt, Wkt, Wvt, Qb, Kb, Vb);

    // 3. V^T + RoPE fused (independent post-QKV transforms, one launch)
    vtrope<<<2048 + (BSZ * (NH + KVH) * 8) / 256, 256, 0, stream>>>(
        Vb, Vtg, Qb, Kb);

    // 4. flash attention (R7 exact), Q-tile 64, heavy-first, 1024 blocks
    attn_mfma<<<dim3(BB, NH, SS / 64), 256, 0, stream>>>(Qb, Kb, Vtg, ctx);

    // 5. out-projection (8-phase 256x128, perfect 256-block fill), XCD-swizzled
    gemm_out<<<dim3(16, 16), 512, 0, stream>>>(ctx, Wot, out);
}